// Round 1
// baseline (104.640 us; speedup 1.0000x reference)
//
#include <hip/hip_runtime.h>
#include <math.h>

#define N 512
#define DIM 128
#define NORM_S 3.0f

// Kernel 1: f = NORM_S * x / ||x||, one wave (64 lanes) per row.
// Also zeros the two accumulators (ws is poisoned 0xAA before every call).
__global__ void __launch_bounds__(64) normalize_kernel(const float* __restrict__ x,
                                                       float* __restrict__ f,
                                                       float* __restrict__ acc) {
    int row = blockIdx.x;
    int lane = threadIdx.x;  // 0..63
    const float2* xr = (const float2*)(x + row * DIM);
    float2 v = xr[lane];
    float s = v.x * v.x + v.y * v.y;
    // butterfly reduce across 64 lanes
    #pragma unroll
    for (int off = 32; off > 0; off >>= 1) s += __shfl_xor(s, off, 64);
    float scale = NORM_S / sqrtf(s);
    float2 fv;
    fv.x = v.x * scale;
    fv.y = v.y * scale;
    ((float2*)(f + row * DIM))[lane] = fv;
    if (row == 0 && lane == 0) { acc[0] = 0.0f; acc[1] = 0.0f; }
}

// Kernel 2: one block per anchor i. Compute D_ij = max(0, 18 - 2 f_i.f_j),
// compact same-class / diff-class D values into LDS lists, then accumulate
// softplus(D_same - D_diff) over the ns x nd product.
__global__ void __launch_bounds__(256) triplet_kernel(const float* __restrict__ f,
                                                      const int* __restrict__ labels,
                                                      float* __restrict__ acc) {
    __shared__ float fi[DIM];
    __shared__ int   lab[N];
    __shared__ float sameD[N];
    __shared__ float diffD[N];
    __shared__ int   nsame, ndiff;
    __shared__ float red[256];

    int i = blockIdx.x;
    int t = threadIdx.x;

    if (t < DIM) fi[t] = f[i * DIM + t];
    for (int j = t; j < N; j += 256) lab[j] = labels[j];
    if (t == 0) { nsame = 0; ndiff = 0; }
    __syncthreads();

    int li = lab[i];

    // D row + classification (2 j's per thread)
    for (int j = t; j < N; j += 256) {
        const float4* fr = (const float4*)(f + j * DIM);
        const float4* fb = (const float4*)fi;
        float dot = 0.0f;
        #pragma unroll
        for (int d = 0; d < DIM / 4; ++d) {
            float4 a = fr[d];
            float4 b = fb[d];
            dot += a.x * b.x + a.y * b.y + a.z * b.z + a.w * b.w;
        }
        float D = fmaxf(0.0f, 2.0f * NORM_S * NORM_S - 2.0f * dot);
        int lj = lab[j];
        if (lj == li) {
            if (j != i) { int p = atomicAdd(&nsame, 1); sameD[p] = D; }
        } else {
            int p = atomicAdd(&ndiff, 1); diffD[p] = D;
        }
    }
    __syncthreads();

    int ns = nsame, nd = ndiff;
    float lsum = 0.0f;
    for (int js = 0; js < ns; ++js) {
        float Dij = sameD[js];
        for (int ks = t; ks < nd; ks += 256) {
            float d = Dij - diffD[ks];
            // stable softplus: log(1+exp(d))
            lsum += fmaxf(d, 0.0f) + log1pf(__expf(-fabsf(d)));
        }
    }

    red[t] = lsum;
    __syncthreads();
    #pragma unroll
    for (int s = 128; s > 0; s >>= 1) {
        if (t < s) red[t] += red[t + s];
        __syncthreads();
    }
    if (t == 0) {
        atomicAdd(&acc[0], red[0]);
        atomicAdd(&acc[1], (float)(ns * nd));
    }
}

__global__ void finalize_kernel(const float* __restrict__ acc, float* __restrict__ out) {
    out[0] = acc[0] / acc[1];
}

extern "C" void kernel_launch(void* const* d_in, const int* in_sizes, int n_in,
                              void* d_out, int out_size, void* d_ws, size_t ws_size,
                              hipStream_t stream) {
    const float* x      = (const float*)d_in[0];
    const int*   labels = (const int*)d_in[1];
    float*       out    = (float*)d_out;

    float* f   = (float*)d_ws;      // 512*128 floats = 256 KB
    float* acc = f + N * DIM;       // acc[0] = loss sum, acc[1] = triplet count

    normalize_kernel<<<N, 64, 0, stream>>>(x, f, acc);
    triplet_kernel<<<N, 256, 0, stream>>>(f, labels, acc);
    finalize_kernel<<<1, 1, 0, stream>>>(acc, out);
}

// Round 2
// 85.745 us; speedup vs baseline: 1.2204x; 1.2204x over previous
//
#include <hip/hip_runtime.h>
#include <math.h>

#define N 512
#define DIM 128
#define NORM_S 3.0f

// ws layout: f[N*DIM] floats | sums[N] | cnts[N]

// Kernel 1: f = NORM_S * x / ||x||, one wave (64 lanes) per row.
__global__ void __launch_bounds__(64) normalize_kernel(const float* __restrict__ x,
                                                       float* __restrict__ f) {
    int row = blockIdx.x;
    int lane = threadIdx.x;  // 0..63
    const float2* xr = (const float2*)(x + row * DIM);
    float2 v = xr[lane];
    float s = v.x * v.x + v.y * v.y;
    #pragma unroll
    for (int off = 32; off > 0; off >>= 1) s += __shfl_xor(s, off, 64);
    float scale = NORM_S / sqrtf(s);
    float2 fv;
    fv.x = v.x * scale;
    fv.y = v.y * scale;
    ((float2*)(f + row * DIM))[lane] = fv;
}

// Kernel 2: one block per anchor i. D_ij = max(0, 18 - 2 f_i.f_j); compact
// same/diff lists in LDS; accumulate softplus(D_same - D_diff); write ONE
// partial sum + count per block (no same-address global atomics).
__global__ void __launch_bounds__(256) triplet_kernel(const float* __restrict__ f,
                                                      const int* __restrict__ labels,
                                                      float* __restrict__ sums,
                                                      float* __restrict__ cnts) {
    __shared__ float fi[DIM];
    __shared__ int   lab[N];
    __shared__ float sameD[N];
    __shared__ float diffD[N];
    __shared__ int   nsame, ndiff;
    __shared__ float red[256];

    int i = blockIdx.x;
    int t = threadIdx.x;

    if (t < DIM) fi[t] = f[i * DIM + t];
    for (int j = t; j < N; j += 256) lab[j] = labels[j];
    if (t == 0) { nsame = 0; ndiff = 0; }
    __syncthreads();

    int li = lab[i];

    for (int j = t; j < N; j += 256) {
        const float4* fr = (const float4*)(f + j * DIM);
        const float4* fb = (const float4*)fi;
        // 4 independent accumulators to break the serial FMA chain
        float d0 = 0.0f, d1 = 0.0f, d2 = 0.0f, d3 = 0.0f;
        #pragma unroll
        for (int d = 0; d < DIM / 4; d += 4) {
            float4 a0 = fr[d + 0], b0 = fb[d + 0];
            float4 a1 = fr[d + 1], b1 = fb[d + 1];
            float4 a2 = fr[d + 2], b2 = fb[d + 2];
            float4 a3 = fr[d + 3], b3 = fb[d + 3];
            d0 += a0.x * b0.x + a0.y * b0.y + a0.z * b0.z + a0.w * b0.w;
            d1 += a1.x * b1.x + a1.y * b1.y + a1.z * b1.z + a1.w * b1.w;
            d2 += a2.x * b2.x + a2.y * b2.y + a2.z * b2.z + a2.w * b2.w;
            d3 += a3.x * b3.x + a3.y * b3.y + a3.z * b3.z + a3.w * b3.w;
        }
        float dot = (d0 + d1) + (d2 + d3);
        float D = fmaxf(0.0f, 2.0f * NORM_S * NORM_S - 2.0f * dot);
        int lj = lab[j];
        if (lj == li) {
            if (j != i) { int p = atomicAdd(&nsame, 1); sameD[p] = D; }
        } else {
            int p = atomicAdd(&ndiff, 1); diffD[p] = D;
        }
    }
    __syncthreads();

    int ns = nsame, nd = ndiff;
    float lsum = 0.0f;
    for (int js = 0; js < ns; ++js) {
        float Dij = sameD[js];
        for (int ks = t; ks < nd; ks += 256) {
            // d in [-36,36]: expf can't overflow fp32; skip stabilization.
            float d = Dij - diffD[ks];
            lsum += __logf(1.0f + __expf(d));
        }
    }

    red[t] = lsum;
    __syncthreads();
    #pragma unroll
    for (int s = 128; s > 0; s >>= 1) {
        if (t < s) red[t] += red[t + s];
        __syncthreads();
    }
    if (t == 0) {
        sums[i] = red[0];
        cnts[i] = (float)(ns * nd);
    }
}

// Kernel 3: reduce the 512 per-block partials (contention-free).
__global__ void __launch_bounds__(256) finalize_kernel(const float* __restrict__ sums,
                                                       const float* __restrict__ cnts,
                                                       float* __restrict__ out) {
    __shared__ float2 red[256];
    int t = threadIdx.x;
    float2 v;
    v.x = sums[t] + sums[t + 256];
    v.y = cnts[t] + cnts[t + 256];
    red[t] = v;
    __syncthreads();
    #pragma unroll
    for (int s = 128; s > 0; s >>= 1) {
        if (t < s) {
            red[t].x += red[t + s].x;
            red[t].y += red[t + s].y;
        }
        __syncthreads();
    }
    if (t == 0) out[0] = red[0].x / red[0].y;
}

extern "C" void kernel_launch(void* const* d_in, const int* in_sizes, int n_in,
                              void* d_out, int out_size, void* d_ws, size_t ws_size,
                              hipStream_t stream) {
    const float* x      = (const float*)d_in[0];
    const int*   labels = (const int*)d_in[1];
    float*       out    = (float*)d_out;

    float* f    = (float*)d_ws;       // 512*128 floats = 256 KB
    float* sums = f + N * DIM;        // 512 floats
    float* cnts = sums + N;           // 512 floats

    normalize_kernel<<<N, 64, 0, stream>>>(x, f);
    triplet_kernel<<<N, 256, 0, stream>>>(f, labels, sums, cnts);
    finalize_kernel<<<1, 256, 0, stream>>>(sums, cnts, out);
}